// Round 5
// baseline (387.756 us; speedup 1.0000x reference)
//
#include <hip/hip_runtime.h>
#include <hip/hip_bf16.h>
#include <stdint.h>

__device__ __forceinline__ int imin(int a, int b) { return a < b ? a : b; }
__device__ __forceinline__ int imax(int a, int b) { return a > b ? a : b; }

#define TMASK ((1u << 19) - 1u)

__constant__ int cRES[16] = {16, 23, 31, 43, 59, 81, 112, 154,
                             213, 295, 407, 562, 777, 1073, 1483, 2048};

// ---------------- Kernel A: hash-grid encode, thread = (point, level) ----------------
// Block: 256 threads, ONE level, 256 consecutive points.  level = blockIdx.x % 16
// (round-robin block->XCD then clusters levels {k,k+8} on XCD k for L2 locality).
// enc layout: [16][N] float2 in d_ws.
__global__ void __launch_bounds__(256) ngp_encode(
    const float* __restrict__ xin,
    const float2* __restrict__ tab,
    float2* __restrict__ enc,
    int n)
{
    const int bid = blockIdx.x;
    const int l = bid & 15;
    const int p = (bid >> 4) * 256 + threadIdx.x;
    if (p >= n) return;

    const int rm = cRES[l] - 1;
    const float rf = (float)rm;

    const float xn0 = (xin[3 * p + 0] + 1.0f) * 0.5f;
    const float xn1 = (xin[3 * p + 1] + 1.0f) * 0.5f;
    const float xn2 = (xin[3 * p + 2] + 1.0f) * 0.5f;

    const float p0 = xn0 * rf, p1 = xn1 * rf, p2 = xn2 * rf;
    const float f0 = floorf(p0), f1 = floorf(p1), f2 = floorf(p2);
    const int i0 = (int)f0, i1 = (int)f1, i2 = (int)f2;
    const float w0 = p0 - f0, w1 = p1 - f1, w2 = p2 - f2;

    const int a0 = imax(imin(i0, rm), 0), b0 = imax(imin(i0 + 1, rm), 0);
    const int a1 = imax(imin(i1, rm), 0), b1 = imax(imin(i1 + 1, rm), 0);
    const int a2 = imax(imin(i2, rm), 0), b2 = imax(imin(i2 + 1, rm), 0);

    const uint32_t t0a = (uint32_t)a0;
    const uint32_t t0b = (uint32_t)b0;
    const uint32_t t1a = (uint32_t)a1 * 2654435761u;
    const uint32_t t1b = (uint32_t)b1 * 2654435761u;
    const uint32_t t2a = (uint32_t)a2 * 805459861u;
    const uint32_t t2b = (uint32_t)b2 * 805459861u;
    const uint32_t base = (uint32_t)l << 19;

    const float2 v000 = tab[base + ((t0a ^ t1a ^ t2a) & TMASK)];
    const float2 v100 = tab[base + ((t0b ^ t1a ^ t2a) & TMASK)];
    const float2 v010 = tab[base + ((t0a ^ t1b ^ t2a) & TMASK)];
    const float2 v110 = tab[base + ((t0b ^ t1b ^ t2a) & TMASK)];
    const float2 v001 = tab[base + ((t0a ^ t1a ^ t2b) & TMASK)];
    const float2 v101 = tab[base + ((t0b ^ t1a ^ t2b) & TMASK)];
    const float2 v011 = tab[base + ((t0a ^ t1b ^ t2b) & TMASK)];
    const float2 v111 = tab[base + ((t0b ^ t1b ^ t2b) & TMASK)];

    const float u0 = 1.0f - w0, u1 = 1.0f - w1, u2 = 1.0f - w2;
    float e0 = 0.0f, e1 = 0.0f;
    {   float cw = u0 * u1 * u2;  e0 = fmaf(v000.x, cw, e0); e1 = fmaf(v000.y, cw, e1); }
    {   float cw = w0 * u1 * u2;  e0 = fmaf(v100.x, cw, e0); e1 = fmaf(v100.y, cw, e1); }
    {   float cw = u0 * w1 * u2;  e0 = fmaf(v010.x, cw, e0); e1 = fmaf(v010.y, cw, e1); }
    {   float cw = w0 * w1 * u2;  e0 = fmaf(v110.x, cw, e0); e1 = fmaf(v110.y, cw, e1); }
    {   float cw = u0 * u1 * w2;  e0 = fmaf(v001.x, cw, e0); e1 = fmaf(v001.y, cw, e1); }
    {   float cw = w0 * u1 * w2;  e0 = fmaf(v101.x, cw, e0); e1 = fmaf(v101.y, cw, e1); }
    {   float cw = u0 * w1 * w2;  e0 = fmaf(v011.x, cw, e0); e1 = fmaf(v011.y, cw, e1); }
    {   float cw = w0 * w1 * w2;  e0 = fmaf(v111.x, cw, e0); e1 = fmaf(v111.y, cw, e1); }

    enc[(size_t)l * n + p] = make_float2(e0, e1);
}

// ---------------- Kernel B: MLPs, thread = point ----------------
__global__ void __launch_bounds__(256) ngp_mlp(
    const float2* __restrict__ enc,   // [16][N]
    const float* __restrict__ din,
    const float* __restrict__ W1,     // [32][64]
    const float* __restrict__ W2,     // [64][16]
    const float* __restrict__ WIN,    // [32][64]
    const float* __restrict__ WH,     // [64][64]
    const float* __restrict__ WOUT,   // [64][3]
    float* __restrict__ out,
    int n)
{
    const int i = blockIdx.x * 256 + threadIdx.x;
    if (i >= n) return;

    float h1[64];
    #pragma unroll
    for (int j = 0; j < 64; ++j) h1[j] = 0.0f;

    #pragma unroll
    for (int l = 0; l < 16; ++l) {
        const float2 e = enc[(size_t)l * n + i];
        #pragma unroll
        for (int j = 0; j < 64; ++j)
            h1[j] = fmaf(e.x, W1[(2 * l) * 64 + j], fmaf(e.y, W1[(2 * l + 1) * 64 + j], h1[j]));
    }

    float h[16];
    #pragma unroll
    for (int j = 0; j < 16; ++j) h[j] = 0.0f;
    #pragma unroll
    for (int k = 0; k < 64; ++k) {
        const float v = fmaxf(h1[k], 0.0f);
        #pragma unroll
        for (int j = 0; j < 16; ++j) h[j] = fmaf(v, W2[k * 16 + j], h[j]);
    }

    out[i] = __expf(h[0]);   // sigma

    const float dx = din[3 * i + 0];
    const float dy = din[3 * i + 1];
    const float dz = din[3 * i + 2];
    const float xy = dx * dy, xz = dx * dz, yz = dy * dz;
    const float x2 = dx * dx, y2 = dy * dy, z2 = dz * dz;

    float sh[16];
    sh[0]  = 0.28209479177387814f;
    sh[1]  = -0.48860251190291987f * dy;
    sh[2]  = 0.48860251190291987f * dz;
    sh[3]  = -0.48860251190291987f * dx;
    sh[4]  = 1.0925484305920792f * xy;
    sh[5]  = -1.0925484305920792f * yz;
    sh[6]  = 0.94617469575756f * z2 - 0.31539156525252f;
    sh[7]  = -1.0925484305920792f * xz;
    sh[8]  = 0.5462742152960396f * (x2 - y2);
    sh[9]  = 0.5900435899266435f * dy * (-3.0f * x2 + y2);
    sh[10] = 2.890611442640554f * xy * dz;
    sh[11] = 0.4570457994644657f * dy * (1.0f - 5.0f * z2);
    sh[12] = 0.3731763325901154f * dz * (5.0f * z2 - 3.0f);
    sh[13] = 0.4570457994644657f * dx * (1.0f - 5.0f * z2);
    sh[14] = 1.445305721320277f * dz * (x2 - y2);
    sh[15] = 0.5900435899266435f * dx * (-x2 + 3.0f * y2);

    float av[64];
    #pragma unroll
    for (int j = 0; j < 64; ++j) av[j] = 0.0f;
    #pragma unroll
    for (int k = 0; k < 16; ++k) {
        const float v = sh[k];
        #pragma unroll
        for (int j = 0; j < 64; ++j) av[j] = fmaf(v, WIN[k * 64 + j], av[j]);
    }
    #pragma unroll
    for (int k = 0; k < 16; ++k) {
        const float v = h[k];
        #pragma unroll
        for (int j = 0; j < 64; ++j) av[j] = fmaf(v, WIN[(16 + k) * 64 + j], av[j]);
    }

    float bv[64];
    #pragma unroll
    for (int j = 0; j < 64; ++j) bv[j] = 0.0f;
    #pragma unroll
    for (int k = 0; k < 64; ++k) {
        const float v = fmaxf(av[k], 0.0f);
        #pragma unroll
        for (int j = 0; j < 64; ++j) bv[j] = fmaf(v, WH[k * 64 + j], bv[j]);
    }

    float r0 = 0.0f, r1 = 0.0f, r2 = 0.0f;
    #pragma unroll
    for (int k = 0; k < 64; ++k) {
        const float v = fmaxf(bv[k], 0.0f);
        r0 = fmaf(v, WOUT[k * 3 + 0], r0);
        r1 = fmaf(v, WOUT[k * 3 + 1], r1);
        r2 = fmaf(v, WOUT[k * 3 + 2], r2);
    }
    out[n + 3 * i + 0] = 1.0f / (1.0f + __expf(-r0));
    out[n + 3 * i + 1] = 1.0f / (1.0f + __expf(-r1));
    out[n + 3 * i + 2] = 1.0f / (1.0f + __expf(-r2));
}

// ---------------- Fallback: proven monolithic kernel (round-3) ----------------
__global__ void __launch_bounds__(256) ngp_main(
    const float* __restrict__ xin,
    const float* __restrict__ din,
    const float2* __restrict__ tab,
    const float* __restrict__ W1,
    const float* __restrict__ W2,
    const float* __restrict__ WIN,
    const float* __restrict__ WH,
    const float* __restrict__ WOUT,
    float* __restrict__ out,
    int n)
{
    const int i = blockIdx.x * 256 + threadIdx.x;
    if (i >= n) return;

    constexpr int RES[16] = {16, 23, 31, 43, 59, 81, 112, 154,
                             213, 295, 407, 562, 777, 1073, 1483, 2048};

    const float xn0 = (xin[3 * i + 0] + 1.0f) * 0.5f;
    const float xn1 = (xin[3 * i + 1] + 1.0f) * 0.5f;
    const float xn2 = (xin[3 * i + 2] + 1.0f) * 0.5f;

    float h1[64];
    #pragma unroll
    for (int j = 0; j < 64; ++j) h1[j] = 0.0f;

    #pragma unroll
    for (int l = 0; l < 16; ++l) {
        const int rm = RES[l] - 1;
        const float rf = (float)rm;
        const float p0 = xn0 * rf, p1 = xn1 * rf, p2 = xn2 * rf;
        const float f0 = floorf(p0), f1 = floorf(p1), f2 = floorf(p2);
        const int i0 = (int)f0, i1 = (int)f1, i2 = (int)f2;
        const float w0 = p0 - f0, w1 = p1 - f1, w2 = p2 - f2;

        const int a0 = imax(imin(i0, rm), 0), b0 = imax(imin(i0 + 1, rm), 0);
        const int a1 = imax(imin(i1, rm), 0), b1 = imax(imin(i1 + 1, rm), 0);
        const int a2 = imax(imin(i2, rm), 0), b2 = imax(imin(i2 + 1, rm), 0);

        const uint32_t t0a = (uint32_t)a0;
        const uint32_t t0b = (uint32_t)b0;
        const uint32_t t1a = (uint32_t)a1 * 2654435761u;
        const uint32_t t1b = (uint32_t)b1 * 2654435761u;
        const uint32_t t2a = (uint32_t)a2 * 805459861u;
        const uint32_t t2b = (uint32_t)b2 * 805459861u;
        const uint32_t base = (uint32_t)l << 19;

        const float2 v000 = tab[base + ((t0a ^ t1a ^ t2a) & TMASK)];
        const float2 v100 = tab[base + ((t0b ^ t1a ^ t2a) & TMASK)];
        const float2 v010 = tab[base + ((t0a ^ t1b ^ t2a) & TMASK)];
        const float2 v110 = tab[base + ((t0b ^ t1b ^ t2a) & TMASK)];
        const float2 v001 = tab[base + ((t0a ^ t1a ^ t2b) & TMASK)];
        const float2 v101 = tab[base + ((t0b ^ t1a ^ t2b) & TMASK)];
        const float2 v011 = tab[base + ((t0a ^ t1b ^ t2b) & TMASK)];
        const float2 v111 = tab[base + ((t0b ^ t1b ^ t2b) & TMASK)];

        const float u0 = 1.0f - w0, u1 = 1.0f - w1, u2 = 1.0f - w2;
        float e0 = 0.0f, e1 = 0.0f;
        {   float cw = u0 * u1 * u2;  e0 = fmaf(v000.x, cw, e0); e1 = fmaf(v000.y, cw, e1); }
        {   float cw = w0 * u1 * u2;  e0 = fmaf(v100.x, cw, e0); e1 = fmaf(v100.y, cw, e1); }
        {   float cw = u0 * w1 * u2;  e0 = fmaf(v010.x, cw, e0); e1 = fmaf(v010.y, cw, e1); }
        {   float cw = w0 * w1 * u2;  e0 = fmaf(v110.x, cw, e0); e1 = fmaf(v110.y, cw, e1); }
        {   float cw = u0 * u1 * w2;  e0 = fmaf(v001.x, cw, e0); e1 = fmaf(v001.y, cw, e1); }
        {   float cw = w0 * u1 * w2;  e0 = fmaf(v101.x, cw, e0); e1 = fmaf(v101.y, cw, e1); }
        {   float cw = u0 * w1 * w2;  e0 = fmaf(v011.x, cw, e0); e1 = fmaf(v011.y, cw, e1); }
        {   float cw = w0 * w1 * w2;  e0 = fmaf(v111.x, cw, e0); e1 = fmaf(v111.y, cw, e1); }

        #pragma unroll
        for (int j = 0; j < 64; ++j)
            h1[j] = fmaf(e0, W1[(2 * l) * 64 + j], fmaf(e1, W1[(2 * l + 1) * 64 + j], h1[j]));
    }

    float h[16];
    #pragma unroll
    for (int j = 0; j < 16; ++j) h[j] = 0.0f;
    #pragma unroll
    for (int k = 0; k < 64; ++k) {
        const float v = fmaxf(h1[k], 0.0f);
        #pragma unroll
        for (int j = 0; j < 16; ++j) h[j] = fmaf(v, W2[k * 16 + j], h[j]);
    }

    out[i] = __expf(h[0]);

    const float dx = din[3 * i + 0];
    const float dy = din[3 * i + 1];
    const float dz = din[3 * i + 2];
    const float xy = dx * dy, xz = dx * dz, yz = dy * dz;
    const float x2 = dx * dx, y2 = dy * dy, z2 = dz * dz;

    float sh[16];
    sh[0]  = 0.28209479177387814f;
    sh[1]  = -0.48860251190291987f * dy;
    sh[2]  = 0.48860251190291987f * dz;
    sh[3]  = -0.48860251190291987f * dx;
    sh[4]  = 1.0925484305920792f * xy;
    sh[5]  = -1.0925484305920792f * yz;
    sh[6]  = 0.94617469575756f * z2 - 0.31539156525252f;
    sh[7]  = -1.0925484305920792f * xz;
    sh[8]  = 0.5462742152960396f * (x2 - y2);
    sh[9]  = 0.5900435899266435f * dy * (-3.0f * x2 + y2);
    sh[10] = 2.890611442640554f * xy * dz;
    sh[11] = 0.4570457994644657f * dy * (1.0f - 5.0f * z2);
    sh[12] = 0.3731763325901154f * dz * (5.0f * z2 - 3.0f);
    sh[13] = 0.4570457994644657f * dx * (1.0f - 5.0f * z2);
    sh[14] = 1.445305721320277f * dz * (x2 - y2);
    sh[15] = 0.5900435899266435f * dx * (-x2 + 3.0f * y2);

    float av[64];
    #pragma unroll
    for (int j = 0; j < 64; ++j) av[j] = 0.0f;
    #pragma unroll
    for (int k = 0; k < 16; ++k) {
        const float v = sh[k];
        #pragma unroll
        for (int j = 0; j < 64; ++j) av[j] = fmaf(v, WIN[k * 64 + j], av[j]);
    }
    #pragma unroll
    for (int k = 0; k < 16; ++k) {
        const float v = h[k];
        #pragma unroll
        for (int j = 0; j < 64; ++j) av[j] = fmaf(v, WIN[(16 + k) * 64 + j], av[j]);
    }

    float bv[64];
    #pragma unroll
    for (int j = 0; j < 64; ++j) bv[j] = 0.0f;
    #pragma unroll
    for (int k = 0; k < 64; ++k) {
        const float v = fmaxf(av[k], 0.0f);
        #pragma unroll
        for (int j = 0; j < 64; ++j) bv[j] = fmaf(v, WH[k * 64 + j], bv[j]);
    }

    float r0 = 0.0f, r1 = 0.0f, r2 = 0.0f;
    #pragma unroll
    for (int k = 0; k < 64; ++k) {
        const float v = fmaxf(bv[k], 0.0f);
        r0 = fmaf(v, WOUT[k * 3 + 0], r0);
        r1 = fmaf(v, WOUT[k * 3 + 1], r1);
        r2 = fmaf(v, WOUT[k * 3 + 2], r2);
    }
    out[n + 3 * i + 0] = 1.0f / (1.0f + __expf(-r0));
    out[n + 3 * i + 1] = 1.0f / (1.0f + __expf(-r1));
    out[n + 3 * i + 2] = 1.0f / (1.0f + __expf(-r2));
}

extern "C" void kernel_launch(void* const* d_in, const int* in_sizes, int n_in,
                              void* d_out, int out_size, void* d_ws, size_t ws_size,
                              hipStream_t stream)
{
    const float* x    = (const float*)d_in[0];
    const float* d    = (const float*)d_in[1];
    const float* tb   = (const float*)d_in[2];
    const float* w1   = (const float*)d_in[3];
    const float* w2   = (const float*)d_in[4];
    const float* win  = (const float*)d_in[5];
    const float* wh   = (const float*)d_in[6];
    const float* wout = (const float*)d_in[7];

    const int n = in_sizes[0] / 3;   // 262144
    const size_t enc_bytes = (size_t)16 * n * sizeof(float2);  // 33.5 MB

    if (ws_size >= enc_bytes) {
        float2* enc = (float2*)d_ws;
        ngp_encode<<<(n / 256) * 16, 256, 0, stream>>>(x, (const float2*)tb, enc, n);
        ngp_mlp<<<n / 256, 256, 0, stream>>>(enc, d, w1, w2, win, wh, wout,
                                             (float*)d_out, n);
    } else {
        ngp_main<<<n / 256, 256, 0, stream>>>(x, d, (const float2*)tb,
                                              w1, w2, win, wh, wout,
                                              (float*)d_out, n);
    }
}

// Round 6
// 249.159 us; speedup vs baseline: 1.5563x; 1.5563x over previous
//
#include <hip/hip_runtime.h>
#include <hip/hip_bf16.h>
#include <stdint.h>

typedef __bf16 bf16x8 __attribute__((ext_vector_type(8)));
typedef float  f32x4  __attribute__((ext_vector_type(4)));

__device__ __forceinline__ int imin(int a, int b) { return a < b ? a : b; }
__device__ __forceinline__ int imax(int a, int b) { return a > b ? a : b; }

#define TMASK ((1u << 19) - 1u)

__constant__ int cRES[16] = {16, 23, 31, 43, 59, 81, 112, 154,
                             213, 295, 407, 562, 777, 1073, 1483, 2048};

// ---------------- Kernel A: hash-grid encode ----------------
// Two launches (lbase = 0, 8). level = lbase + (bid & 7) so with round-robin
// block->XCD dispatch each XCD's L2 sees exactly ONE 4 MB table window.
// enc output stored non-temporally so it doesn't evict the table from L2.
__global__ void __launch_bounds__(256) ngp_encode(
    const float* __restrict__ xin,
    const float2* __restrict__ tab,
    float2* __restrict__ enc,
    int n, int lbase)
{
    const int bid = blockIdx.x;
    const int l = lbase + (bid & 7);
    const int p = (bid >> 3) * 256 + threadIdx.x;
    if (p >= n) return;

    const int rm = cRES[l] - 1;
    const float rf = (float)rm;

    const float xn0 = (xin[3 * p + 0] + 1.0f) * 0.5f;
    const float xn1 = (xin[3 * p + 1] + 1.0f) * 0.5f;
    const float xn2 = (xin[3 * p + 2] + 1.0f) * 0.5f;

    const float p0 = xn0 * rf, p1 = xn1 * rf, p2 = xn2 * rf;
    const float f0 = floorf(p0), f1 = floorf(p1), f2 = floorf(p2);
    const int i0 = (int)f0, i1 = (int)f1, i2 = (int)f2;
    const float w0 = p0 - f0, w1 = p1 - f1, w2 = p2 - f2;

    const int a0 = imax(imin(i0, rm), 0), b0 = imax(imin(i0 + 1, rm), 0);
    const int a1 = imax(imin(i1, rm), 0), b1 = imax(imin(i1 + 1, rm), 0);
    const int a2 = imax(imin(i2, rm), 0), b2 = imax(imin(i2 + 1, rm), 0);

    const uint32_t t0a = (uint32_t)a0;
    const uint32_t t0b = (uint32_t)b0;
    const uint32_t t1a = (uint32_t)a1 * 2654435761u;
    const uint32_t t1b = (uint32_t)b1 * 2654435761u;
    const uint32_t t2a = (uint32_t)a2 * 805459861u;
    const uint32_t t2b = (uint32_t)b2 * 805459861u;
    const uint32_t base = (uint32_t)l << 19;

    const float2 v000 = tab[base + ((t0a ^ t1a ^ t2a) & TMASK)];
    const float2 v100 = tab[base + ((t0b ^ t1a ^ t2a) & TMASK)];
    const float2 v010 = tab[base + ((t0a ^ t1b ^ t2a) & TMASK)];
    const float2 v110 = tab[base + ((t0b ^ t1b ^ t2a) & TMASK)];
    const float2 v001 = tab[base + ((t0a ^ t1a ^ t2b) & TMASK)];
    const float2 v101 = tab[base + ((t0b ^ t1a ^ t2b) & TMASK)];
    const float2 v011 = tab[base + ((t0a ^ t1b ^ t2b) & TMASK)];
    const float2 v111 = tab[base + ((t0b ^ t1b ^ t2b) & TMASK)];

    const float u0 = 1.0f - w0, u1 = 1.0f - w1, u2 = 1.0f - w2;
    float e0 = 0.0f, e1 = 0.0f;
    {   float cw = u0 * u1 * u2;  e0 = fmaf(v000.x, cw, e0); e1 = fmaf(v000.y, cw, e1); }
    {   float cw = w0 * u1 * u2;  e0 = fmaf(v100.x, cw, e0); e1 = fmaf(v100.y, cw, e1); }
    {   float cw = u0 * w1 * u2;  e0 = fmaf(v010.x, cw, e0); e1 = fmaf(v010.y, cw, e1); }
    {   float cw = w0 * w1 * u2;  e0 = fmaf(v110.x, cw, e0); e1 = fmaf(v110.y, cw, e1); }
    {   float cw = u0 * u1 * w2;  e0 = fmaf(v001.x, cw, e0); e1 = fmaf(v001.y, cw, e1); }
    {   float cw = w0 * u1 * w2;  e0 = fmaf(v101.x, cw, e0); e1 = fmaf(v101.y, cw, e1); }
    {   float cw = u0 * w1 * w2;  e0 = fmaf(v011.x, cw, e0); e1 = fmaf(v011.y, cw, e1); }
    {   float cw = w0 * w1 * w2;  e0 = fmaf(v111.x, cw, e0); e1 = fmaf(v111.y, cw, e1); }

    union { double d; float2 f; } u;
    u.f = make_float2(e0, e1);
    __builtin_nontemporal_store(u.d, (double*)&enc[(size_t)l * n + p]);
}

// ---------------- Kernel B: MFMA MLP ----------------
// Wave = 16 points. 20x mfma_f32_16x16x32_bf16 per tile.
// Fragment layouts (gfx950, verified in guide):
//   A[row][k]: row = lane&15, k = 8*(lane>>4)+j
//   B[k][col]: col = lane&15, k = 8*(lane>>4)+j
//   D[row][col]: col = lane&15, row = 4*(lane>>4)+reg
// Inter-layer transpose via per-wave LDS tile [16][68] (stride 68 floats:
// b128 reads land 8 req/bank uniform = optimal; writes 2-way = free).
__global__ void __launch_bounds__(256) ngp_mlp_mfma(
    const float2* __restrict__ enc,   // [16][N]
    const float* __restrict__ din,
    const float* __restrict__ W1,     // [32][64]
    const float* __restrict__ W2,     // [64][16]
    const float* __restrict__ WIN,    // [32][64]
    const float* __restrict__ WH,     // [64][64]
    const float* __restrict__ WOUT,   // [64][3]
    float* __restrict__ out,
    int n, int ntiles)
{
    __shared__ float lds[4][16 * 68];
    const int tid  = threadIdx.x;
    const int wid  = tid >> 6;
    const int lane = tid & 63;
    const int c = lane & 15;   // A-row (point) / B-col / D-col
    const int g = lane >> 4;   // k-group
    float* buf = &lds[wid][0];

    // ---- load weight fragments once (held in VGPRs across the tile loop) ----
    bf16x8 w1f[4], w2f[2], winf[4], whf[2][4], woutf[2];
    #pragma unroll
    for (int n4 = 0; n4 < 4; ++n4)
        #pragma unroll
        for (int j = 0; j < 8; ++j)
            w1f[n4][j] = (__bf16)W1[(g * 8 + j) * 64 + n4 * 16 + c];
    #pragma unroll
    for (int kc = 0; kc < 2; ++kc)
        #pragma unroll
        for (int j = 0; j < 8; ++j)
            w2f[kc][j] = (__bf16)W2[(kc * 32 + g * 8 + j) * 16 + c];
    #pragma unroll
    for (int n4 = 0; n4 < 4; ++n4)
        #pragma unroll
        for (int j = 0; j < 8; ++j)
            winf[n4][j] = (__bf16)WIN[(g * 8 + j) * 64 + n4 * 16 + c];
    #pragma unroll
    for (int kc = 0; kc < 2; ++kc)
        #pragma unroll
        for (int n4 = 0; n4 < 4; ++n4)
            #pragma unroll
            for (int j = 0; j < 8; ++j)
                whf[kc][n4][j] = (__bf16)WH[(kc * 32 + g * 8 + j) * 64 + n4 * 16 + c];
    #pragma unroll
    for (int kc = 0; kc < 2; ++kc)
        #pragma unroll
        for (int j = 0; j < 8; ++j)
            woutf[kc][j] = (c < 3) ? (__bf16)WOUT[(kc * 32 + g * 8 + j) * 3 + c]
                                   : (__bf16)0.0f;

    for (int t = blockIdx.x; t < ntiles; t += gridDim.x) {
        const int pbase = t * 64 + wid * 16;
        const int pc = pbase + c;

        // ---- A1 from enc: feats k=8g..8g+7 = levels 4g..4g+3 x {x,y} ----
        bf16x8 a1;
        #pragma unroll
        for (int m = 0; m < 4; ++m) {
            const float2 e = enc[(size_t)(4 * g + m) * n + pc];
            a1[2 * m]     = (__bf16)e.x;
            a1[2 * m + 1] = (__bf16)e.y;
        }

        // ---- layer 1: D1 = A1 @ W1 ; relu -> LDS [16pt][64f] ----
        #pragma unroll
        for (int n4 = 0; n4 < 4; ++n4) {
            f32x4 d = {0.f, 0.f, 0.f, 0.f};
            d = __builtin_amdgcn_mfma_f32_16x16x32_bf16(a1, w1f[n4], d, 0, 0, 0);
            #pragma unroll
            for (int r = 0; r < 4; ++r)
                buf[(g * 4 + r) * 68 + n4 * 16 + c] = fmaxf(d[r], 0.0f);
        }

        // ---- layer 2: h = relu(h1) @ W2 (K=64 -> 2 chunks, N=16) ----
        f32x4 hacc = {0.f, 0.f, 0.f, 0.f};
        #pragma unroll
        for (int kc = 0; kc < 2; ++kc) {
            bf16x8 a2;
            const float* src = &buf[c * 68 + kc * 32 + g * 8];
            #pragma unroll
            for (int j = 0; j < 8; ++j) a2[j] = (__bf16)src[j];
            hacc = __builtin_amdgcn_mfma_f32_16x16x32_bf16(a2, w2f[kc], hacc, 0, 0, 0);
        }

        // sigma = exp(h[:,0])
        if (c == 0) {
            #pragma unroll
            for (int r = 0; r < 4; ++r)
                out[pbase + g * 4 + r] = __expf(hacc[r]);
        }

        // stage raw h into LDS cols 0..15
        #pragma unroll
        for (int r = 0; r < 4; ++r)
            buf[(g * 4 + r) * 68 + c] = hacc[r];

        // ---- SH degree 4 for point pc (every lane computes its own) ----
        const float dx = din[3 * pc + 0];
        const float dy = din[3 * pc + 1];
        const float dz = din[3 * pc + 2];
        const float xy = dx * dy, xz = dx * dz, yz = dy * dz;
        const float x2 = dx * dx, y2 = dy * dy, z2 = dz * dz;
        float shv[16];
        shv[0]  = 0.28209479177387814f;
        shv[1]  = -0.48860251190291987f * dy;
        shv[2]  = 0.48860251190291987f * dz;
        shv[3]  = -0.48860251190291987f * dx;
        shv[4]  = 1.0925484305920792f * xy;
        shv[5]  = -1.0925484305920792f * yz;
        shv[6]  = 0.94617469575756f * z2 - 0.31539156525252f;
        shv[7]  = -1.0925484305920792f * xz;
        shv[8]  = 0.5462742152960396f * (x2 - y2);
        shv[9]  = 0.5900435899266435f * dy * (-3.0f * x2 + y2);
        shv[10] = 2.890611442640554f * xy * dz;
        shv[11] = 0.4570457994644657f * dy * (1.0f - 5.0f * z2);
        shv[12] = 0.3731763325901154f * dz * (5.0f * z2 - 3.0f);
        shv[13] = 0.4570457994644657f * dx * (1.0f - 5.0f * z2);
        shv[14] = 1.445305721320277f * dz * (x2 - y2);
        shv[15] = 0.5900435899266435f * dx * (-x2 + 3.0f * y2);

        // ---- A3 = concat([sh, h]) : k 0..15 sh, 16..31 h ----
        bf16x8 a3;
        if (g < 2) {
            #pragma unroll
            for (int j = 0; j < 8; ++j) a3[j] = (__bf16)shv[g * 8 + j];
        } else {
            const float* hsrc = &buf[c * 68 + (g - 2) * 8];
            #pragma unroll
            for (int j = 0; j < 8; ++j) a3[j] = (__bf16)hsrc[j];
        }

        // ---- layer 3: D3 = A3 @ WIN ; relu -> LDS ----
        #pragma unroll
        for (int n4 = 0; n4 < 4; ++n4) {
            f32x4 d = {0.f, 0.f, 0.f, 0.f};
            d = __builtin_amdgcn_mfma_f32_16x16x32_bf16(a3, winf[n4], d, 0, 0, 0);
            #pragma unroll
            for (int r = 0; r < 4; ++r)
                buf[(g * 4 + r) * 68 + n4 * 16 + c] = fmaxf(d[r], 0.0f);
        }

        // ---- layer 4: D4 = A4 @ WH (2 k-chunks x 4 n-tiles) ; relu -> LDS ----
        bf16x8 a4[2];
        #pragma unroll
        for (int kc = 0; kc < 2; ++kc) {
            const float* src = &buf[c * 68 + kc * 32 + g * 8];
            #pragma unroll
            for (int j = 0; j < 8; ++j) a4[kc][j] = (__bf16)src[j];
        }
        f32x4 d4[4];
        #pragma unroll
        for (int n4 = 0; n4 < 4; ++n4) d4[n4] = (f32x4){0.f, 0.f, 0.f, 0.f};
        #pragma unroll
        for (int kc = 0; kc < 2; ++kc)
            #pragma unroll
            for (int n4 = 0; n4 < 4; ++n4)
                d4[n4] = __builtin_amdgcn_mfma_f32_16x16x32_bf16(a4[kc], whf[kc][n4], d4[n4], 0, 0, 0);
        #pragma unroll
        for (int n4 = 0; n4 < 4; ++n4)
            #pragma unroll
            for (int r = 0; r < 4; ++r)
                buf[(g * 4 + r) * 68 + n4 * 16 + c] = fmaxf(d4[n4][r], 0.0f);

        // ---- layer 5: D5 = A5 @ WOUT(pad16) ; sigmoid ; store rgb ----
        f32x4 d5 = {0.f, 0.f, 0.f, 0.f};
        #pragma unroll
        for (int kc = 0; kc < 2; ++kc) {
            bf16x8 a5;
            const float* src = &buf[c * 68 + kc * 32 + g * 8];
            #pragma unroll
            for (int j = 0; j < 8; ++j) a5[j] = (__bf16)src[j];
            d5 = __builtin_amdgcn_mfma_f32_16x16x32_bf16(a5, woutf[kc], d5, 0, 0, 0);
        }
        if (c < 3) {
            #pragma unroll
            for (int r = 0; r < 4; ++r)
                out[n + 3 * (pbase + g * 4 + r) + c] = 1.0f / (1.0f + __expf(-d5[r]));
        }
    }
}

// ---------------- Fallback scalar MLP (proven, used only if ws too small path changes) ----------------
__global__ void __launch_bounds__(256) ngp_mlp(
    const float2* __restrict__ enc, const float* __restrict__ din,
    const float* __restrict__ W1, const float* __restrict__ W2,
    const float* __restrict__ WIN, const float* __restrict__ WH,
    const float* __restrict__ WOUT, float* __restrict__ out, int n)
{
    const int i = blockIdx.x * 256 + threadIdx.x;
    if (i >= n) return;
    float h1[64];
    #pragma unroll
    for (int j = 0; j < 64; ++j) h1[j] = 0.0f;
    #pragma unroll
    for (int l = 0; l < 16; ++l) {
        const float2 e = enc[(size_t)l * n + i];
        #pragma unroll
        for (int j = 0; j < 64; ++j)
            h1[j] = fmaf(e.x, W1[(2 * l) * 64 + j], fmaf(e.y, W1[(2 * l + 1) * 64 + j], h1[j]));
    }
    float h[16];
    #pragma unroll
    for (int j = 0; j < 16; ++j) h[j] = 0.0f;
    #pragma unroll
    for (int k = 0; k < 64; ++k) {
        const float v = fmaxf(h1[k], 0.0f);
        #pragma unroll
        for (int j = 0; j < 16; ++j) h[j] = fmaf(v, W2[k * 16 + j], h[j]);
    }
    out[i] = __expf(h[0]);
    const float dx = din[3 * i + 0], dy = din[3 * i + 1], dz = din[3 * i + 2];
    const float xy = dx * dy, xz = dx * dz, yz = dy * dz;
    const float x2 = dx * dx, y2 = dy * dy, z2 = dz * dz;
    float sh[16];
    sh[0]  = 0.28209479177387814f;
    sh[1]  = -0.48860251190291987f * dy;
    sh[2]  = 0.48860251190291987f * dz;
    sh[3]  = -0.48860251190291987f * dx;
    sh[4]  = 1.0925484305920792f * xy;
    sh[5]  = -1.0925484305920792f * yz;
    sh[6]  = 0.94617469575756f * z2 - 0.31539156525252f;
    sh[7]  = -1.0925484305920792f * xz;
    sh[8]  = 0.5462742152960396f * (x2 - y2);
    sh[9]  = 0.5900435899266435f * dy * (-3.0f * x2 + y2);
    sh[10] = 2.890611442640554f * xy * dz;
    sh[11] = 0.4570457994644657f * dy * (1.0f - 5.0f * z2);
    sh[12] = 0.3731763325901154f * dz * (5.0f * z2 - 3.0f);
    sh[13] = 0.4570457994644657f * dx * (1.0f - 5.0f * z2);
    sh[14] = 1.445305721320277f * dz * (x2 - y2);
    sh[15] = 0.5900435899266435f * dx * (-x2 + 3.0f * y2);
    float av[64];
    #pragma unroll
    for (int j = 0; j < 64; ++j) av[j] = 0.0f;
    #pragma unroll
    for (int k = 0; k < 16; ++k) {
        const float v = sh[k];
        #pragma unroll
        for (int j = 0; j < 64; ++j) av[j] = fmaf(v, WIN[k * 64 + j], av[j]);
    }
    #pragma unroll
    for (int k = 0; k < 16; ++k) {
        const float v = h[k];
        #pragma unroll
        for (int j = 0; j < 64; ++j) av[j] = fmaf(v, WIN[(16 + k) * 64 + j], av[j]);
    }
    float bv[64];
    #pragma unroll
    for (int j = 0; j < 64; ++j) bv[j] = 0.0f;
    #pragma unroll
    for (int k = 0; k < 64; ++k) {
        const float v = fmaxf(av[k], 0.0f);
        #pragma unroll
        for (int j = 0; j < 64; ++j) bv[j] = fmaf(v, WH[k * 64 + j], bv[j]);
    }
    float r0 = 0.0f, r1 = 0.0f, r2 = 0.0f;
    #pragma unroll
    for (int k = 0; k < 64; ++k) {
        const float v = fmaxf(bv[k], 0.0f);
        r0 = fmaf(v, WOUT[k * 3 + 0], r0);
        r1 = fmaf(v, WOUT[k * 3 + 1], r1);
        r2 = fmaf(v, WOUT[k * 3 + 2], r2);
    }
    out[n + 3 * i + 0] = 1.0f / (1.0f + __expf(-r0));
    out[n + 3 * i + 1] = 1.0f / (1.0f + __expf(-r1));
    out[n + 3 * i + 2] = 1.0f / (1.0f + __expf(-r2));
}

extern "C" void kernel_launch(void* const* d_in, const int* in_sizes, int n_in,
                              void* d_out, int out_size, void* d_ws, size_t ws_size,
                              hipStream_t stream)
{
    const float* x    = (const float*)d_in[0];
    const float* d    = (const float*)d_in[1];
    const float* tb   = (const float*)d_in[2];
    const float* w1   = (const float*)d_in[3];
    const float* w2   = (const float*)d_in[4];
    const float* win  = (const float*)d_in[5];
    const float* wh   = (const float*)d_in[6];
    const float* wout = (const float*)d_in[7];

    const int n = in_sizes[0] / 3;   // 262144
    const size_t enc_bytes = (size_t)16 * n * sizeof(float2);  // 33.5 MB
    float2* enc = (float2*)d_ws;

    // encode: one level per XCD per launch
    ngp_encode<<<(n / 256) * 8, 256, 0, stream>>>(x, (const float2*)tb, enc, n, 0);
    ngp_encode<<<(n / 256) * 8, 256, 0, stream>>>(x, (const float2*)tb, enc, n, 8);

    if (ws_size >= enc_bytes) {
        const int ntiles = n / 64;   // 4096
        ngp_mlp_mfma<<<512, 256, 0, stream>>>(enc, d, w1, w2, win, wh, wout,
                                              (float*)d_out, n, ntiles);
    } else {
        ngp_mlp<<<n / 256, 256, 0, stream>>>(enc, d, w1, w2, win, wh, wout,
                                             (float*)d_out, n);
    }
}